// Round 2
// baseline (164.399 us; speedup 1.0000x reference)
//
#include <hip/hip_runtime.h>

#define ROWS   32768      // 8*4096 indices
#define DIM4   128        // 512 floats per row = 128 float4
#define BLOCK  256
#define UNROLL 4

using f32x4 = __attribute__((ext_vector_type(4))) float;

__global__ __launch_bounds__(BLOCK) void embed_gather_kernel(
    const int* __restrict__ idx,
    const f32x4* __restrict__ W,
    f32x4* __restrict__ out)
{
    const int t      = blockIdx.x * BLOCK + threadIdx.x;
    const int stride = (ROWS * DIM4) / UNROLL;   // 1,048,576 float4 (multiple of 128)

    f32x4 v[UNROLL];
#pragma unroll
    for (int u = 0; u < UNROLL; ++u) {
        const int pos = t + u * stride;
        const int row = pos >> 7;          // output row (wave-uniform per 64 lanes)
        const int col = pos & (DIM4 - 1);
        const int id  = idx[row];
        v[u] = W[(size_t)id * DIM4 + col]; // 4 independent 16B gathers in flight
    }
#pragma unroll
    for (int u = 0; u < UNROLL; ++u) {
        // out is write-once: nontemporal store, don't evict W from L2/L3
        __builtin_nontemporal_store(v[u], &out[t + u * stride]);
    }
}

extern "C" void kernel_launch(void* const* d_in, const int* in_sizes, int n_in,
                              void* d_out, int out_size, void* d_ws, size_t ws_size,
                              hipStream_t stream) {
    const int*   idx = (const int*)d_in[0];
    const f32x4* W   = (const f32x4*)d_in[1];
    f32x4*       out = (f32x4*)d_out;

    const int total4 = ROWS * DIM4;                 // 4,194,304 float4
    const int grid   = total4 / (BLOCK * UNROLL);   // 4096 blocks, exact
    embed_gather_kernel<<<grid, BLOCK, 0, stream>>>(idx, W, out);
}

// Round 3
// 160.969 us; speedup vs baseline: 1.0213x; 1.0213x over previous
//
#include <hip/hip_runtime.h>

#define ROWS  32768      // 8*4096 indices
#define DIM4  128        // 512 floats per row = 128 float4
#define BLOCK 256
#define WPB   (BLOCK / 64)   // waves per block
#define RPW   4              // rows per wave

using f32x4 = __attribute__((ext_vector_type(4))) float;

__global__ __launch_bounds__(BLOCK) void embed_gather_kernel(
    const int* __restrict__ idx,
    const f32x4* __restrict__ W,
    f32x4* __restrict__ out)
{
    const int wave = blockIdx.x * WPB + (threadIdx.x >> 6);
    const int lane = threadIdx.x & 63;
    const int row0 = wave * RPW;

    // Scalar (s_load) index fetches: row index forced wave-uniform.
    int id[RPW];
#pragma unroll
    for (int r = 0; r < RPW; ++r) {
        const int rr = __builtin_amdgcn_readfirstlane(row0 + r);
        id[r] = idx[rr];
    }

    // 8 independent 16B gathers in flight per lane (one wave = one full 2KB row).
    f32x4 v[RPW][2];
#pragma unroll
    for (int r = 0; r < RPW; ++r) {
        const size_t base = (size_t)id[r] * DIM4;
        v[r][0] = W[base + lane];
        v[r][1] = W[base + lane + 64];
    }

#pragma unroll
    for (int r = 0; r < RPW; ++r) {
        const size_t obase = (size_t)(row0 + r) * DIM4;
        out[obase + lane]      = v[r][0];
        out[obase + lane + 64] = v[r][1];
    }
}

extern "C" void kernel_launch(void* const* d_in, const int* in_sizes, int n_in,
                              void* d_out, int out_size, void* d_ws, size_t ws_size,
                              hipStream_t stream) {
    const int*   idx = (const int*)d_in[0];
    const f32x4* W   = (const f32x4*)d_in[1];
    f32x4*       out = (f32x4*)d_out;

    const int grid = ROWS / (RPW * WPB);   // 2048 blocks, exact
    embed_gather_kernel<<<grid, BLOCK, 0, stream>>>(idx, W, out);
}